// Round 1
// baseline (163.832 us; speedup 1.0000x reference)
//
#include <hip/hip_runtime.h>
#include <stdint.h>

// Moment features: all monomials of degree <= 4 over 16 latent dims.
// Output [B,T,4845] fp32, write-bound (~158.8 MB). Each channel is a product
// of <=4 input elements; channel order replicates the reference's
// _build_indices + np.nonzero(row-major) enumeration exactly, built constexpr.

#define D    16
#define NC   4845   // 1 + 16 + 136 + 816 + 3876 = C(20,4)
#define N2   136
#define N4   3876
#define LDSZ 153    // 17 (x[0..15], 1.0) + 136 (pairwise products)

struct Tables {
    unsigned short chan[NC];   // per channel: two 8-bit indices into LDS array; value = lds[lo]*lds[hi]
    unsigned short p2pair[N2]; // slot m -> (k | j<<8), j<=k, for staging p2[m] = x[k]*x[j]
};

static constexpr int slot2(int a, int b) { return a * (a + 1) / 2 + b; } // a>=b

static constexpr Tables build_tables() {
    Tables t{};
    long c[D] = {};
    for (int i = 0; i < D; ++i) c[i] = 1;
    int tupPrev[N4][4] = {};
    int tupNext[N4][4] = {};
    for (int i = 0; i < D; ++i) {
        tupPrev[i][0] = i; tupPrev[i][1] = 16; tupPrev[i][2] = 16; tupPrev[i][3] = 16;
    }
    int pos = 0;
    // order-0 (ones): 1.0 * 1.0
    t.chan[pos++] = (unsigned short)(16 | (16 << 8));
    // order-1: x[i] * 1.0
    for (int i = 0; i < D; ++i) t.chan[pos++] = (unsigned short)(i | (16 << 8));
    // orders 2..4, replicating _build_indices exactly
    for (int it = 0; it < 3; ++it) {
        long S[D] = {};
        long acc = 0;
        for (int i = D - 1; i >= 0; --i) { acc += c[i]; S[i] = acc; }
        const long n = S[0];
        long off[D] = {};
        for (int i = 0; i < D; ++i) off[i] = n - S[i];
        const int len = it + 2;     // tuple length after appending
        int cnt = 0;
        for (long k = 0; k < n; ++k) {          // row-major: k major, j minor (np.nonzero order)
            for (int j = 0; j < D; ++j) {
                if (k >= off[j]) {
                    int nt[4];
                    for (int q = 0; q < 4; ++q) nt[q] = tupPrev[k][q];
                    nt[len - 1] = j;
                    for (int q = 0; q < 4; ++q) tupNext[cnt][q] = nt[q];
                    ++cnt;
                    // sort the len real indices descending
                    int s[4] = {16, 16, 16, 16};
                    for (int q = 0; q < len; ++q) s[q] = nt[q];
                    for (int a = 1; a < len; ++a) {
                        int v = s[a]; int b = a - 1;
                        while (b >= 0 && s[b] < v) { s[b + 1] = s[b]; --b; }
                        s[b + 1] = v;
                    }
                    unsigned e;
                    if (len == 2)      e = (unsigned)s[0] | ((unsigned)s[1] << 8);
                    else if (len == 3) e = (unsigned)(17 + slot2(s[0], s[1])) | ((unsigned)s[2] << 8);
                    else               e = (unsigned)(17 + slot2(s[0], s[1]))
                                         | ((unsigned)(17 + slot2(s[2], s[3])) << 8);
                    t.chan[pos++] = (unsigned short)e;
                }
            }
        }
        for (int i = 0; i < D; ++i) c[i] = S[i];
        for (int i = 0; i < cnt; ++i)
            for (int q = 0; q < 4; ++q) tupPrev[i][q] = tupNext[i][q];
    }
    // p2 staging pairs: slot m = k(k+1)/2 + j  (k major, j minor, j<=k)
    int m = 0;
    for (int k = 0; k < D; ++k)
        for (int j = 0; j <= k; ++j)
            t.p2pair[m++] = (unsigned short)(k | (j << 8));
    return t;
}

__device__ const Tables d_tables = build_tables();

__global__ __launch_bounds__(256) void moment_kernel(const float* __restrict__ in,
                                                     float* __restrict__ out,
                                                     int npos) {
    __shared__ float lds[LDSZ];
    const int pos = blockIdx.x;
    if (pos >= npos) return;
    const int tid = threadIdx.x;

    const float* __restrict__ xrow = in + (size_t)pos * D;
    if (tid < D) lds[tid] = xrow[tid];
    if (tid == D) lds[D] = 1.0f;          // identity slot
    __syncthreads();

    if (tid < N2) {
        const unsigned pk = d_tables.p2pair[tid];
        lds[17 + tid] = lds[pk & 0xFFu] * lds[pk >> 8];
    }
    __syncthreads();

    float* __restrict__ orow = out + (size_t)pos * NC;
    for (int c = tid; c < NC; c += 256) {
        const unsigned e = d_tables.chan[c];
        orow[c] = lds[e & 0xFFu] * lds[e >> 8];   // coalesced dword store
    }
}

extern "C" void kernel_launch(void* const* d_in, const int* in_sizes, int n_in,
                              void* d_out, int out_size, void* d_ws, size_t ws_size,
                              hipStream_t stream) {
    const float* in = (const float*)d_in[0];
    float* out = (float*)d_out;
    const int npos = in_sizes[0] / D;   // B*T = 8192
    moment_kernel<<<npos, 256, 0, stream>>>(in, out, npos);
}

// Round 2
// 161.128 us; speedup vs baseline: 1.0168x; 1.0168x over previous
//
#include <hip/hip_runtime.h>
#include <stdint.h>

// Moment features: all monomials of degree <= 4 over 16 latent dims.
// Output [8192, 4845] fp32 (~158.8 MB) -> pure HBM-write-bound.
//
// Strategy: 4845 dwords/row is odd, but 4 rows = 19380 dwords = exactly 4845
// 16B-aligned float4 chunks. One block handles 4 positions; the mapping
// flat-dword -> (pos_local, lo_idx, hi_idx) is identical for every block, so
// it is baked into a constexpr u32 table (final LDS indices pre-added).
// Inner loop: 1 dwordx4 table load + 8 LDS reads + 4 muls + 1 dwordx4 store.

#define D      16
#define NC     4845    // 1 + 16 + 136 + 816 + 3876 = C(20,4)
#define N2     136
#define N4     3876
#define POSPB  4                 // positions (rows) per block
#define FLATPB (NC * POSPB)      // 19380 dwords per block
#define STRIDE 153               // value slots per position: x[16], 1.0, p2[136]

struct Tables {
    uint32_t chunk[FLATPB];   // (pos*STRIDE+lo) | ((pos*STRIDE+hi) << 16)
    uint16_t p2pair[N2];      // slot m -> (k | j<<8), j<=k
};

static constexpr int slot2(int a, int b) { return a * (a + 1) / 2 + b; } // a>=b

static constexpr Tables build_tables() {
    Tables t{};
    // ---- per-channel (lo,hi) into the 153-slot value array, in exact
    // reference enumeration order (replicates _build_indices + np.nonzero) ----
    unsigned short chan[NC] = {};
    long c[D] = {};
    for (int i = 0; i < D; ++i) c[i] = 1;
    int tupPrev[N4][4] = {};
    int tupNext[N4][4] = {};
    for (int i = 0; i < D; ++i) {
        tupPrev[i][0] = i; tupPrev[i][1] = 16; tupPrev[i][2] = 16; tupPrev[i][3] = 16;
    }
    int pos = 0;
    chan[pos++] = (unsigned short)(16 | (16 << 8));              // order-0: 1*1
    for (int i = 0; i < D; ++i)
        chan[pos++] = (unsigned short)(i | (16 << 8));           // order-1: x[i]*1
    for (int it = 0; it < 3; ++it) {
        long S[D] = {};
        long acc = 0;
        for (int i = D - 1; i >= 0; --i) { acc += c[i]; S[i] = acc; }
        const long n = S[0];
        long off[D] = {};
        for (int i = 0; i < D; ++i) off[i] = n - S[i];
        const int len = it + 2;
        int cnt = 0;
        for (long k = 0; k < n; ++k) {            // row-major (np.nonzero order)
            for (int j = 0; j < D; ++j) {
                if (k >= off[j]) {
                    int nt[4];
                    for (int q = 0; q < 4; ++q) nt[q] = tupPrev[k][q];
                    nt[len - 1] = j;
                    for (int q = 0; q < 4; ++q) tupNext[cnt][q] = nt[q];
                    ++cnt;
                    int s[4] = {16, 16, 16, 16};
                    for (int q = 0; q < len; ++q) s[q] = nt[q];
                    for (int a = 1; a < len; ++a) {            // sort descending
                        int v = s[a]; int b = a - 1;
                        while (b >= 0 && s[b] < v) { s[b + 1] = s[b]; --b; }
                        s[b + 1] = v;
                    }
                    unsigned e;
                    if (len == 2)      e = (unsigned)s[0] | ((unsigned)s[1] << 8);
                    else if (len == 3) e = (unsigned)(17 + slot2(s[0], s[1])) | ((unsigned)s[2] << 8);
                    else               e = (unsigned)(17 + slot2(s[0], s[1]))
                                         | ((unsigned)(17 + slot2(s[2], s[3])) << 8);
                    chan[pos++] = (unsigned short)e;
                }
            }
        }
        for (int i = 0; i < D; ++i) c[i] = S[i];
        for (int i = 0; i < cnt; ++i)
            for (int q = 0; q < 4; ++q) tupPrev[i][q] = tupNext[i][q];
    }
    // ---- expand per flat dword of a 4-row group, baking pos_local ----
    for (int f = 0; f < FLATPB; ++f) {
        int p = f / NC;
        int ch = f - p * NC;
        unsigned lo = chan[ch] & 0xFFu;
        unsigned hi = chan[ch] >> 8;
        t.chunk[f] = (uint32_t)(p * STRIDE + lo) | ((uint32_t)(p * STRIDE + hi) << 16);
    }
    // ---- p2 staging pairs: slot m = k(k+1)/2 + j, j<=k ----
    int m = 0;
    for (int k = 0; k < D; ++k)
        for (int j = 0; j <= k; ++j)
            t.p2pair[m++] = (unsigned short)(k | (j << 8));
    return t;
}

__device__ const Tables d_tables = build_tables();

__global__ __launch_bounds__(256) void moment_kernel(const float* __restrict__ in,
                                                     float* __restrict__ out) {
    __shared__ float vals[POSPB * STRIDE];
    const int tid = threadIdx.x;
    const int blk = blockIdx.x;

    // stage x: 4 rows * 16 floats = 256 B, as 16 float4 loads
    if (tid < 16) {
        float4 v = reinterpret_cast<const float4*>(in + (size_t)blk * (POSPB * D))[tid];
        const int p  = tid >> 2;
        const int i0 = (tid & 3) * 4;
        vals[p * STRIDE + i0 + 0] = v.x;
        vals[p * STRIDE + i0 + 1] = v.y;
        vals[p * STRIDE + i0 + 2] = v.z;
        vals[p * STRIDE + i0 + 3] = v.w;
    } else if (tid < 16 + POSPB) {
        vals[(tid - 16) * STRIDE + 16] = 1.0f;   // identity slot
    }
    __syncthreads();

    // stage pairwise products for all 4 positions
    if (tid < N2) {
        const unsigned pk = d_tables.p2pair[tid];
        const unsigned a = pk & 0xFFu, b = pk >> 8;
        #pragma unroll
        for (int p = 0; p < POSPB; ++p)
            vals[p * STRIDE + 17 + tid] = vals[p * STRIDE + a] * vals[p * STRIDE + b];
    }
    __syncthreads();

    // main loop: 4845 float4 chunks per block, fully coalesced 16B stores
    float4* __restrict__ ochunk = reinterpret_cast<float4*>(out + (size_t)blk * FLATPB);
    const uint4* __restrict__ tab = reinterpret_cast<const uint4*>(d_tables.chunk);
    for (int q = tid; q < NC; q += 256) {
        const uint4 e = tab[q];
        float4 v;
        v.x = vals[e.x & 0xFFFFu] * vals[e.x >> 16];
        v.y = vals[e.y & 0xFFFFu] * vals[e.y >> 16];
        v.z = vals[e.z & 0xFFFFu] * vals[e.z >> 16];
        v.w = vals[e.w & 0xFFFFu] * vals[e.w >> 16];
        ochunk[q] = v;
    }
}

extern "C" void kernel_launch(void* const* d_in, const int* in_sizes, int n_in,
                              void* d_out, int out_size, void* d_ws, size_t ws_size,
                              hipStream_t stream) {
    const float* in = (const float*)d_in[0];
    float* out = (float*)d_out;
    const int npos = in_sizes[0] / D;        // 8192
    const int nblk = npos / POSPB;           // 2048
    moment_kernel<<<nblk, 256, 0, stream>>>(in, out);
}